// Round 1
// baseline (129.040 us; speedup 1.0000x reference)
//
#include <hip/hip_runtime.h>
#include <hip/hip_bf16.h>
#include <math.h>

// ---------------- problem constants ----------------
#define N_ROWS 8192
#define DIM    512
#define NCLS   64
#define BM     128   // tile rows/cols
#define BK     64    // K step
#define M_CONST 14.285714285714286f       // 1/0.07 == fixed max-shift (diagonal)
#define SCALE_SQRT 3.7796447300922722f    // sqrt(1/0.07): fold /T into the operands

using bf16x8 = __attribute__((ext_vector_type(8))) short;
using f32x4  = __attribute__((ext_vector_type(4))) float;

static __device__ inline unsigned short f2bf(float x) {
  unsigned u = __float_as_uint(x);
  unsigned r = u + 0x7FFFu + ((u >> 16) & 1u);   // RNE
  return (unsigned short)(r >> 16);
}

// ---------------- kernel 1: L2-normalize rows, scale by sqrt(1/T), cast bf16 ----
__global__ __launch_bounds__(256) void normalize_rows(const float* __restrict__ proj,
                                                      unsigned short* __restrict__ outb) {
  const int row  = blockIdx.x * 4 + (threadIdx.x >> 6);
  const int lane = threadIdx.x & 63;
  const float4* src = (const float4*)(proj + (size_t)row * DIM);
  float4 a = src[lane * 2];
  float4 b = src[lane * 2 + 1];
  float ss = a.x*a.x + a.y*a.y + a.z*a.z + a.w*a.w
           + b.x*b.x + b.y*b.y + b.z*b.z + b.w*b.w;
#pragma unroll
  for (int off = 1; off < 64; off <<= 1) ss += __shfl_xor(ss, off);
  const float scale = SCALE_SQRT / fmaxf(sqrtf(ss), 1e-12f);
  float v[8] = {a.x, a.y, a.z, a.w, b.x, b.y, b.z, b.w};
  unsigned short h[8];
#pragma unroll
  for (int i = 0; i < 8; ++i) h[i] = f2bf(v[i] * scale);
  uint4 packed;
  packed.x = (unsigned)h[0] | ((unsigned)h[1] << 16);
  packed.y = (unsigned)h[2] | ((unsigned)h[3] << 16);
  packed.z = (unsigned)h[4] | ((unsigned)h[5] << 16);
  packed.w = (unsigned)h[6] | ((unsigned)h[7] << 16);
  *(uint4*)(outb + (size_t)row * DIM + lane * 8) = packed;
}

// ---------------- kernel 2: class histogram (cnt_i = hist[t_i]-1) --------------
__global__ __launch_bounds__(256) void class_hist(const int* __restrict__ tgt,
                                                  int* __restrict__ hist) {
  __shared__ int h[NCLS];
  if (threadIdx.x < NCLS) h[threadIdx.x] = 0;
  __syncthreads();
  for (int i = threadIdx.x; i < N_ROWS; i += 256) atomicAdd(&h[tgt[i]], 1);
  __syncthreads();
  if (threadIdx.x < NCLS) hist[threadIdx.x] = h[threadIdx.x];
}

// ---------------- kernel 3: upper-tri tile GEMM + fused reduction epilogue ------
// Tile (br,bc), bc>=br. 4 waves as 2x2 quadrants of 64x64; mfma 16x16x32 bf16.
// Row-path partial for row r goes to slot (bc*2+wc); col-path (transpose
// contribution, bc>br only) for col c goes to slot (br*2+wr). 128 slots total,
// each [slot][row] written exactly once -> deterministic, no init needed.
__global__ __launch_bounds__(256) void supcon_tile(const unsigned short* __restrict__ p16,
                                                   const int* __restrict__ tgt,
                                                   float* __restrict__ dpart,
                                                   float* __restrict__ spart) {
  const int bc = blockIdx.x, br = blockIdx.y;
  if (bc < br) return;   // upper triangle only (uniform exit)

  __shared__ short As[BM * BK];   // 16 KB  [row][k] row-major, 128B rows
  __shared__ short Bs[BM * BK];   // 16 KB
  __shared__ int tgr[BM], tgc[BM];

  const int tid  = threadIdx.x;
  const int lane = tid & 63;
  const int wid  = tid >> 6;
  const int wr = wid >> 1, wc = wid & 1;
  const int lhi = lane >> 4, llo = lane & 15;

  if (tid < BM)            tgr[tid] = tgt[br * BM + tid];
  else if (tid < 2 * BM)   tgc[tid - BM] = tgt[bc * BM + (tid - BM)];

  f32x4 zero = {0.f, 0.f, 0.f, 0.f};
  f32x4 acc[4][4];
#pragma unroll
  for (int i = 0; i < 4; ++i)
#pragma unroll
    for (int j = 0; j < 4; ++j) acc[i][j] = zero;

  const int r_ld = tid >> 3;        // 0..31: row within 32-row staging chunk
  const int c_ld = (tid & 7) * 8;   // col offset in shorts (16B granule)
  const size_t rowA0 = (size_t)br * BM;
  const size_t rowB0 = (size_t)bc * BM;

  for (int kt = 0; kt < DIM / BK; ++kt) {
    __syncthreads();   // previous compute done before overwriting LDS
#pragma unroll
    for (int c = 0; c < 4; ++c) {
      const int r = c * 32 + r_ld;
      const unsigned short* gA = p16 + (rowA0 + r) * DIM + kt * BK + c_ld;
      const unsigned short* gB = p16 + (rowB0 + r) * DIM + kt * BK + c_ld;
      __builtin_amdgcn_global_load_lds((const __attribute__((address_space(1))) void*)gA,
                                       (__attribute__((address_space(3))) void*)&As[r * BK + c_ld],
                                       16, 0, 0);
      __builtin_amdgcn_global_load_lds((const __attribute__((address_space(1))) void*)gB,
                                       (__attribute__((address_space(3))) void*)&Bs[r * BK + c_ld],
                                       16, 0, 0);
    }
    __syncthreads();   // compiler drains vmcnt before barrier
#pragma unroll
    for (int ks = 0; ks < 2; ++ks) {
      bf16x8 af[4], bfr[4];
#pragma unroll
      for (int mi = 0; mi < 4; ++mi)
        af[mi] = *(const bf16x8*)&As[(wr * 64 + mi * 16 + llo) * BK + ks * 32 + lhi * 8];
#pragma unroll
      for (int ni = 0; ni < 4; ++ni)
        bfr[ni] = *(const bf16x8*)&Bs[(wc * 64 + ni * 16 + llo) * BK + ks * 32 + lhi * 8];
#pragma unroll
      for (int mi = 0; mi < 4; ++mi)
#pragma unroll
        for (int ni = 0; ni < 4; ++ni)
          acc[mi][ni] = __builtin_amdgcn_mfma_f32_16x16x32_bf16(af[mi], bfr[ni], acc[mi][ni], 0, 0, 0);
    }
  }

  // ---- epilogue: e = exp(sim - M) (self zeroed), s = sim if positive pair ----
  const bool diag = (br == bc);
  float ecol[4] = {0.f, 0.f, 0.f, 0.f};
  float scol[4] = {0.f, 0.f, 0.f, 0.f};

#pragma unroll
  for (int mi = 0; mi < 4; ++mi) {
#pragma unroll
    for (int rg = 0; rg < 4; ++rg) {
      const int rin  = wr * 64 + mi * 16 + lhi * 4 + rg;   // row within tile
      const int trow = tgr[rin];
      float esum = 0.f, ssum = 0.f;
#pragma unroll
      for (int ni = 0; ni < 4; ++ni) {
        const int cin = wc * 64 + ni * 16 + llo;           // col within tile
        const float sim = acc[mi][ni][rg];
        const bool self = diag && (rin == cin);
        const float e = self ? 0.f : __expf(sim - M_CONST);
        const bool pos = (!self) && (trow == tgc[cin]);
        const float sv = pos ? sim : 0.f;
        esum += e;  ssum += sv;
        ecol[ni] += e;  scol[ni] += sv;
      }
      // reduce this row across the 16 column lanes (same lhi group)
#pragma unroll
      for (int off = 1; off < 16; off <<= 1) {
        esum += __shfl_xor(esum, off);
        ssum += __shfl_xor(ssum, off);
      }
      if (llo == 0) {
        const int grow = br * BM + rin;
        dpart[(size_t)(bc * 2 + wc) * N_ROWS + grow] = esum;
        spart[(size_t)(bc * 2 + wc) * N_ROWS + grow] = ssum;
      }
    }
  }

  if (!diag) {  // transpose contribution: column sums -> rows of block bc
#pragma unroll
    for (int ni = 0; ni < 4; ++ni) {
      float ec = ecol[ni], sc = scol[ni];
      ec += __shfl_xor(ec, 16); ec += __shfl_xor(ec, 32);
      sc += __shfl_xor(sc, 16); sc += __shfl_xor(sc, 32);
      if (lhi == 0) {
        const int gcol = bc * BM + wc * 64 + ni * 16 + llo;
        dpart[(size_t)(br * 2 + wr) * N_ROWS + gcol] = ec;
        spart[(size_t)(br * 2 + wr) * N_ROWS + gcol] = sc;
      }
    }
  }
}

// ---------------- kernel 4: combine partials -> per-sample loss ----------------
__global__ __launch_bounds__(256) void combine_loss(const float* __restrict__ dpart,
                                                    const float* __restrict__ spart,
                                                    const int* __restrict__ tgt,
                                                    const int* __restrict__ hist,
                                                    float* __restrict__ out) {
  __shared__ float dsh[4][64], ssh[4][64];
  const int lane = threadIdx.x & 63;
  const int g    = threadIdx.x >> 6;
  const int r    = blockIdx.x * 64 + lane;
  float d = 0.f, s = 0.f;
  for (int k = g * 32; k < g * 32 + 32; ++k) {
    d += dpart[(size_t)k * N_ROWS + r];
    s += spart[(size_t)k * N_ROWS + r];
  }
  dsh[g][lane] = d; ssh[g][lane] = s;
  __syncthreads();
  if (g == 0) {
    d = dsh[0][lane] + dsh[1][lane] + dsh[2][lane] + dsh[3][lane];
    s = ssh[0][lane] + ssh[1][lane] + ssh[2][lane] + ssh[3][lane];
    const int cnt = hist[tgt[r]] - 1;
    out[r] = (cnt > 0) ? (s / (float)cnt - M_CONST - logf(d + 1e-8f)) : 0.f;
  }
}

// ---------------- launcher ----------------
extern "C" void kernel_launch(void* const* d_in, const int* in_sizes, int n_in,
                              void* d_out, int out_size, void* d_ws, size_t ws_size,
                              hipStream_t stream) {
  const float* proj = (const float*)d_in[0];
  const int*   tgt  = (const int*)d_in[1];
  float* out = (float*)d_out;

  char* ws = (char*)d_ws;
  unsigned short* p16  = (unsigned short*)ws;                        // 8 MB
  float* dpart = (float*)(ws + (size_t)8  * 1024 * 1024);            // 4 MB (128 x 8192)
  float* spart = (float*)(ws + (size_t)12 * 1024 * 1024);            // 4 MB
  int*   hist  = (int*)(ws + (size_t)16 * 1024 * 1024);              // 256 B

  normalize_rows<<<N_ROWS / 4, 256, 0, stream>>>(proj, p16);
  class_hist<<<1, 256, 0, stream>>>(tgt, hist);
  dim3 grid(N_ROWS / BM, N_ROWS / BM);   // upper triangle does the work
  supcon_tile<<<grid, 256, 0, stream>>>(p16, tgt, dpart, spart);
  combine_loss<<<N_ROWS / 64, 256, 0, stream>>>(dpart, spart, tgt, hist, out);
}

// Round 2
// 91.872 us; speedup vs baseline: 1.4046x; 1.4046x over previous
//
#include <hip/hip_runtime.h>
#include <hip/hip_bf16.h>
#include <math.h>

// ---------------- problem constants ----------------
#define N_ROWS 8192
#define DIM    512
#define NCLS   64
#define BM     128   // tile rows/cols
#define BK     64    // K step
#define NTILE  (N_ROWS / BM)                 // 64 tile-blocks per side
#define NTRI   (NTILE * (NTILE + 1) / 2)     // 2080 upper-tri tiles
#define M_CONST 14.285714285714286f          // 1/0.07 == fixed max-shift (diagonal)
#define SCALE_SQRT 3.7796447300922722f       // sqrt(1/0.07): fold /T into operands

using bf16x8 = __attribute__((ext_vector_type(8))) short;
using f32x4  = __attribute__((ext_vector_type(4))) float;

static __device__ inline unsigned short f2bf(float x) {
  unsigned u = __float_as_uint(x);
  unsigned r = u + 0x7FFFu + ((u >> 16) & 1u);   // RNE
  return (unsigned short)(r >> 16);
}

// ---------------- kernel 1: L2-normalize rows, scale by sqrt(1/T), cast bf16 ----
__global__ __launch_bounds__(256) void normalize_rows(const float* __restrict__ proj,
                                                      unsigned short* __restrict__ outb) {
  const int row  = blockIdx.x * 4 + (threadIdx.x >> 6);
  const int lane = threadIdx.x & 63;
  const float4* src = (const float4*)(proj + (size_t)row * DIM);
  float4 a = src[lane * 2];
  float4 b = src[lane * 2 + 1];
  float ss = a.x*a.x + a.y*a.y + a.z*a.z + a.w*a.w
           + b.x*b.x + b.y*b.y + b.z*b.z + b.w*b.w;
#pragma unroll
  for (int off = 1; off < 64; off <<= 1) ss += __shfl_xor(ss, off);
  const float scale = SCALE_SQRT / fmaxf(sqrtf(ss), 1e-12f);
  float v[8] = {a.x, a.y, a.z, a.w, b.x, b.y, b.z, b.w};
  unsigned short h[8];
#pragma unroll
  for (int i = 0; i < 8; ++i) h[i] = f2bf(v[i] * scale);
  uint4 packed;
  packed.x = (unsigned)h[0] | ((unsigned)h[1] << 16);
  packed.y = (unsigned)h[2] | ((unsigned)h[3] << 16);
  packed.z = (unsigned)h[4] | ((unsigned)h[5] << 16);
  packed.w = (unsigned)h[6] | ((unsigned)h[7] << 16);
  *(uint4*)(outb + (size_t)row * DIM + lane * 8) = packed;
}

// ---------------- kernel 2: class histogram, wave-privatized ------------------
__global__ __launch_bounds__(1024) void class_hist(const int* __restrict__ tgt,
                                                   int* __restrict__ hist) {
  __shared__ int h[16][NCLS];
  const int wid = threadIdx.x >> 6;
  const int lane = threadIdx.x & 63;
  if (lane < NCLS) h[wid][lane] = 0;
  __syncthreads();
  for (int i = threadIdx.x; i < N_ROWS; i += 1024) atomicAdd(&h[wid][tgt[i]], 1);
  __syncthreads();
  if (threadIdx.x < NCLS) {
    int s = 0;
#pragma unroll
    for (int w = 0; w < 16; ++w) s += h[w][threadIdx.x];
    hist[threadIdx.x] = s;
  }
}

// ---------------- kernel 3: upper-tri tile GEMM + fused reduction epilogue ------
// Exact triangular 1D grid (2080 blocks). Double-buffered LDS (2-phase schedule:
// issue next K-step's global_load_lds before current compute). LDS XOR-swizzle
// applied as pre-swizzled GLOBAL source (linear LDS dest, required by
// global_load_lds) + matching XOR on the ds_read side -> conflict-free b128 reads.
__global__ __launch_bounds__(256, 2) void supcon_tile(const unsigned short* __restrict__ p16,
                                                      const int* __restrict__ tgt,
                                                      float* __restrict__ dpart,
                                                      float* __restrict__ spart) {
  // decode linear block id -> (br, bc) with bc >= br (row-major upper triangle)
  int rem = blockIdx.x, br = 0;
  while (rem >= NTILE - br) { rem -= NTILE - br; ++br; }
  const int bc = br + rem;

  __shared__ short As[2][BM * BK];   // 2 x 16 KB
  __shared__ short Bs[2][BM * BK];   // 2 x 16 KB
  __shared__ int tgr[BM], tgc[BM];

  const int tid  = threadIdx.x;
  const int lane = tid & 63;
  const int wid  = tid >> 6;
  const int wr = wid >> 1, wc = wid & 1;
  const int lhi = lane >> 4, llo = lane & 15;
  const int lsw = llo & 7;           // read-side swizzle key (== row & 7)

  const int r_ld = tid >> 3;         // 0..31: row within 32-row staging chunk
  const int gp   = tid & 7;          // physical 16B granule this thread fills
  const size_t rowA0 = (size_t)br * BM;
  const size_t rowB0 = (size_t)bc * BM;

#define STAGE(BUF, KT) do {                                                          \
  _Pragma("unroll")                                                                  \
  for (int c = 0; c < 4; ++c) {                                                      \
    const int r  = c * 32 + r_ld;                                                    \
    const int gl = gp ^ (r & 7);     /* pre-swizzled global granule */               \
    const unsigned short* gA = p16 + (rowA0 + r) * DIM + (KT) * BK + gl * 8;         \
    const unsigned short* gB = p16 + (rowB0 + r) * DIM + (KT) * BK + gl * 8;         \
    __builtin_amdgcn_global_load_lds((const __attribute__((address_space(1))) void*)gA, \
        (__attribute__((address_space(3))) void*)&As[BUF][r * BK + gp * 8], 16, 0, 0);  \
    __builtin_amdgcn_global_load_lds((const __attribute__((address_space(1))) void*)gB, \
        (__attribute__((address_space(3))) void*)&Bs[BUF][r * BK + gp * 8], 16, 0, 0);  \
  }                                                                                  \
} while (0)

  STAGE(0, 0);
  if (tid < BM)            tgr[tid] = tgt[br * BM + tid];
  else if (tid < 2 * BM)   tgc[tid - BM] = tgt[bc * BM + (tid - BM)];

  f32x4 zero = {0.f, 0.f, 0.f, 0.f};
  f32x4 acc[4][4];
#pragma unroll
  for (int i = 0; i < 4; ++i)
#pragma unroll
    for (int j = 0; j < 4; ++j) acc[i][j] = zero;

  __syncthreads();   // prologue stage drained (compiler emits vmcnt(0) before barrier)

  int cur = 0;
  for (int kt = 0; kt < DIM / BK; ++kt) {
    if (kt + 1 < DIM / BK) STAGE(cur ^ 1, kt + 1);   // prefetch next K-step
#pragma unroll
    for (int ks = 0; ks < 2; ++ks) {
      bf16x8 af[4], bfr[4];
#pragma unroll
      for (int mi = 0; mi < 4; ++mi) {
        const int Ra = wr * 64 + mi * 16 + llo;
        af[mi] = *(const bf16x8*)&As[cur][Ra * BK + (((ks * 4 + lhi) ^ lsw) * 8)];
      }
#pragma unroll
      for (int ni = 0; ni < 4; ++ni) {
        const int Rb = wc * 64 + ni * 16 + llo;
        bfr[ni] = *(const bf16x8*)&Bs[cur][Rb * BK + (((ks * 4 + lhi) ^ lsw) * 8)];
      }
#pragma unroll
      for (int mi = 0; mi < 4; ++mi)
#pragma unroll
        for (int ni = 0; ni < 4; ++ni)
          acc[mi][ni] = __builtin_amdgcn_mfma_f32_16x16x32_bf16(af[mi], bfr[ni], acc[mi][ni], 0, 0, 0);
    }
    __syncthreads();   // drains prefetch vmcnt + compute lgkm; buffer ready
    cur ^= 1;
  }
#undef STAGE

  // ---- epilogue: e = exp(sim - M) (self zeroed), s = sim if positive pair ----
  const bool diag = (br == bc);
  float ecol[4] = {0.f, 0.f, 0.f, 0.f};
  float scol[4] = {0.f, 0.f, 0.f, 0.f};

#pragma unroll
  for (int mi = 0; mi < 4; ++mi) {
#pragma unroll
    for (int rg = 0; rg < 4; ++rg) {
      const int rin  = wr * 64 + mi * 16 + lhi * 4 + rg;   // row within tile
      const int trow = tgr[rin];
      float esum = 0.f, ssum = 0.f;
#pragma unroll
      for (int ni = 0; ni < 4; ++ni) {
        const int cin = wc * 64 + ni * 16 + llo;           // col within tile
        const float sim = acc[mi][ni][rg];
        const bool self = diag && (rin == cin);
        const float e = self ? 0.f : __expf(sim - M_CONST);
        const bool pos = (!self) && (trow == tgc[cin]);
        const float sv = pos ? sim : 0.f;
        esum += e;  ssum += sv;
        ecol[ni] += e;  scol[ni] += sv;
      }
      // reduce this row across the 16 column lanes (same lhi group)
#pragma unroll
      for (int off = 1; off < 16; off <<= 1) {
        esum += __shfl_xor(esum, off);
        ssum += __shfl_xor(ssum, off);
      }
      if (llo == 0) {
        const int grow = br * BM + rin;
        dpart[(size_t)(bc * 2 + wc) * N_ROWS + grow] = esum;
        spart[(size_t)(bc * 2 + wc) * N_ROWS + grow] = ssum;
      }
    }
  }

  if (!diag) {  // transpose contribution: column sums -> rows of block bc
#pragma unroll
    for (int ni = 0; ni < 4; ++ni) {
      float ec = ecol[ni], sc = scol[ni];
      ec += __shfl_xor(ec, 16); ec += __shfl_xor(ec, 32);
      sc += __shfl_xor(sc, 16); sc += __shfl_xor(sc, 32);
      if (lhi == 0) {
        const int gcol = bc * BM + wc * 64 + ni * 16 + llo;
        dpart[(size_t)(br * 2 + wr) * N_ROWS + gcol] = ec;
        spart[(size_t)(br * 2 + wr) * N_ROWS + gcol] = sc;
      }
    }
  }
}

// ---------------- kernel 4: combine partials -> per-sample loss ----------------
__global__ __launch_bounds__(256) void combine_loss(const float* __restrict__ dpart,
                                                    const float* __restrict__ spart,
                                                    const int* __restrict__ tgt,
                                                    const int* __restrict__ hist,
                                                    float* __restrict__ out) {
  __shared__ float dsh[4][64], ssh[4][64];
  const int lane = threadIdx.x & 63;
  const int g    = threadIdx.x >> 6;
  const int r    = blockIdx.x * 64 + lane;
  float d = 0.f, s = 0.f;
  for (int k = g * 32; k < g * 32 + 32; ++k) {
    d += dpart[(size_t)k * N_ROWS + r];
    s += spart[(size_t)k * N_ROWS + r];
  }
  dsh[g][lane] = d; ssh[g][lane] = s;
  __syncthreads();
  if (g == 0) {
    d = dsh[0][lane] + dsh[1][lane] + dsh[2][lane] + dsh[3][lane];
    s = ssh[0][lane] + ssh[1][lane] + ssh[2][lane] + ssh[3][lane];
    const int cnt = hist[tgt[r]] - 1;
    out[r] = (cnt > 0) ? (s / (float)cnt - M_CONST - logf(d + 1e-8f)) : 0.f;
  }
}

// ---------------- launcher ----------------
extern "C" void kernel_launch(void* const* d_in, const int* in_sizes, int n_in,
                              void* d_out, int out_size, void* d_ws, size_t ws_size,
                              hipStream_t stream) {
  const float* proj = (const float*)d_in[0];
  const int*   tgt  = (const int*)d_in[1];
  float* out = (float*)d_out;

  char* ws = (char*)d_ws;
  unsigned short* p16  = (unsigned short*)ws;                        // 8 MB
  float* dpart = (float*)(ws + (size_t)8  * 1024 * 1024);            // 4 MB (128 x 8192)
  float* spart = (float*)(ws + (size_t)12 * 1024 * 1024);            // 4 MB
  int*   hist  = (int*)(ws + (size_t)16 * 1024 * 1024);              // 256 B

  normalize_rows<<<N_ROWS / 4, 256, 0, stream>>>(proj, p16);
  class_hist<<<1, 1024, 0, stream>>>(tgt, hist);
  supcon_tile<<<NTRI, 256, 0, stream>>>(p16, tgt, dpart, spart);
  combine_loss<<<N_ROWS / 64, 256, 0, stream>>>(dpart, spart, tgt, hist, out);
}